// Round 14
// baseline (406.199 us; speedup 1.0000x reference)
//
#include <hip/hip_runtime.h>

typedef unsigned short u16;
typedef unsigned int uint32;
typedef __attribute__((ext_vector_type(8))) short short8;
typedef __attribute__((ext_vector_type(4))) float float4v;

#define N_NODES 50000
#define N_EDGES 800000
#define N_TOT   850000
#define SCAN_BLOCKS ((N_NODES + 255) / 256)

__device__ __forceinline__ float b2f(u16 u) {
  return __uint_as_float(((unsigned int)u) << 16);
}
__device__ __forceinline__ u16 f2b(float f) {
  unsigned int x = __float_as_uint(f);
  unsigned int r = (x + 0x7fffu + ((x >> 16) & 1u)) >> 16;
  return (u16)r;
}
__device__ __forceinline__ float lo_bf(uint32 g) { return __uint_as_float(g << 16); }
__device__ __forceinline__ float hi_bf(uint32 g) { return __uint_as_float(g & 0xffff0000u); }
__device__ __forceinline__ u16 conv_elem(const void* src, int i, int isf32) {
  if (isf32) return f2b(((const float*)src)[i]);
  return ((const u16*)src)[i];
}
__device__ __forceinline__ float lrelu(float a) { return (a >= 0.f) ? a : 0.2f * a; }
// edge_index element i (flat [2,E]); int64 mode reads low word (ids < 2^31)
__device__ __forceinline__ int eget(const int* __restrict__ ei, int i, int isI64) {
  return isI64 ? ei[2 * i] : ei[i];
}

// ---------------- dtype detection ----------------
// flags[0]=1 if float inputs are fp32 (else bf16); flags[1]=1 if edge_index is int64.
__global__ void detect_mode(const u16* __restrict__ x16, const int* __restrict__ ei32,
                            int* __restrict__ flags) {
  __shared__ int sh_f32, sh_i32;
  int tid = threadIdx.x;
  if (tid == 0) { sh_f32 = 0; sh_i32 = 0; }
  __syncthreads();
  int emax = 0;
  for (int i = tid; i < 4096; i += 256) {
    int e = (x16[i] >> 7) & 0xFF;  // bf16 exponent field
    emax = emax > e ? emax : e;
  }
  if (emax >= 140) atomicOr(&sh_f32, 1);           // |v| >= 2^13: impossible for real bf16 N(0,1)
  if (ei32[2 * tid + 1] != 0) atomicOr(&sh_i32, 1); // nonzero odd word => int32 data
  __syncthreads();
  if (tid == 0) { flags[0] = sh_f32; flags[1] = sh_i32 ? 0 : 1; }
}

__global__ void convert_x4(const void* __restrict__ x, const int* __restrict__ flags,
                           u16* __restrict__ out, int n4) {
  int i = blockIdx.x * blockDim.x + threadIdx.x;
  if (i >= n4) return;
  if (flags[0]) {
    float4 v = ((const float4*)x)[i];
    ushort4 o;
    o.x = f2b(v.x); o.y = f2b(v.y); o.z = f2b(v.z); o.w = f2b(v.w);
    ((ushort4*)out)[i] = o;
  } else {
    ((ushort4*)out)[i] = ((const ushort4*)x)[i];
  }
}

// ---------------- W fragment reorder (direct from raw inputs) + att/bias convert ----------
// Wf[t][c][lane][j] = W[c*32 + (lane>>4)*8 + j][t*16 + (lane&15)], zero-padded.
// Tail threads (idx >= 57344) convert the 1063 att/bias elements into wt.
__global__ void reorder_all(const void* W1, const void* W2, const void* W3,
                            const void* a1s, const void* a1d, const void* b1,
                            const void* a2s, const void* a2d, const void* b2,
                            const void* a3s, const void* a3d, const void* b3,
                            const int* __restrict__ flags,
                            u16* __restrict__ Wf1, u16* __restrict__ Wf2,
                            u16* __restrict__ Wf3, u16* __restrict__ wt) {
  int idx = blockIdx.x * blockDim.x + threadIdx.x;
  int f32 = flags[0];
  if (idx < 57344) {
    const void* W; u16* Wf; int NCOLS, li;
    if (idx < 16384)      { W = W1; Wf = Wf1; NCOLS = 128; li = idx; }
    else if (idx < 32768) { W = W2; Wf = Wf2; NCOLS = 128; li = idx - 16384; }
    else                  { W = W3; Wf = Wf3; NCOLS = 188; li = idx - 32768; }
    int j = li & 7;
    int l = (li >> 3) & 63;
    int c = (li >> 9) & 3;
    int t = li >> 11;
    int k = c * 32 + (l >> 4) * 8 + j;
    int n = t * 16 + (l & 15);
    Wf[li] = (n < NCOLS) ? conv_elem(W, k * NCOLS + n, f32) : (u16)0;
  } else {
    int li = idx - 57344;
    const void* src; int off;
    if (li < 128)       { src = a1s; off = 16384; }
    else if (li < 256)  { src = a1d; off = 16512; li -= 128; }
    else if (li < 384)  { src = b1;  off = 16640; li -= 256; }
    else if (li < 512)  { src = a2s; off = 33152; li -= 384; }
    else if (li < 640)  { src = a2d; off = 33280; li -= 512; }
    else if (li < 768)  { src = b2;  off = 33408; li -= 640; }
    else if (li < 956)  { src = a3s; off = 57600; li -= 768; }
    else if (li < 1144) { src = a3d; off = 57788; li -= 956; }
    else if (li < 1191) { src = b3;  off = 57976; li -= 1144; }
    else return;
    wt[off + li] = conv_elem(src, li, f32);
  }
}

// ---------------- CSR build ----------------
// deg is zeroed via hipMemsetAsync; self-loop +1 folded into scan_blocks.
// Node ids < 65536 -> CSR stored as u16 (halves scatter-line count & read bytes).
// dst is NEVER scattered: written as contiguous runs in scan_add.

__global__ void count_deg(const int* __restrict__ ei, const int* __restrict__ flags,
                          int* __restrict__ deg, int nE) {
  int e = blockIdx.x * blockDim.x + threadIdx.x;
  if (e < nE) atomicAdd(&deg[eget(ei, nE + e, flags[1])], 1);
}

// ---- device-wide exclusive scan of (deg+1) (3 kernels, all CUs) ----
__global__ __launch_bounds__(256) void scan_blocks(const int* __restrict__ deg,
                                                   int* __restrict__ part,
                                                   int* __restrict__ bsum, int n) {
  __shared__ int ws[4];
  int tid = threadIdx.x;
  int gid = blockIdx.x * 256 + tid;
  int lane = tid & 63, wv = tid >> 6;
  int v = (gid < n) ? (deg[gid] + 1) : 0;  // +1 = self-loop
  int incl = v;
#pragma unroll
  for (int off = 1; off < 64; off <<= 1) {
    int t = __shfl_up(incl, off, 64);
    if (lane >= off) incl += t;
  }
  if (lane == 63) ws[wv] = incl;
  __syncthreads();
  if (tid == 0) {
    int s = 0;
#pragma unroll
    for (int w = 0; w < 4; w++) { int t = ws[w]; ws[w] = s; s += t; }
    bsum[blockIdx.x] = s;
  }
  __syncthreads();
  if (gid < n) part[gid] = ws[wv] + incl - v;  // exclusive within block
}

__global__ __launch_bounds__(256) void scan_bsum(const int* __restrict__ bsum,
                                                 int* __restrict__ boff,
                                                 int* __restrict__ total, int nb) {
  __shared__ int ws[4];
  int tid = threadIdx.x;
  int lane = tid & 63, wv = tid >> 6;
  int v = (tid < nb) ? bsum[tid] : 0;
  int incl = v;
#pragma unroll
  for (int off = 1; off < 64; off <<= 1) {
    int t = __shfl_up(incl, off, 64);
    if (lane >= off) incl += t;
  }
  if (lane == 63) ws[wv] = incl;
  __syncthreads();
  if (tid == 0) {
    int s = 0;
#pragma unroll
    for (int w = 0; w < 4; w++) { int t = ws[w]; ws[w] = s; s += t; }
    *total = s;
  }
  __syncthreads();
  if (tid < nb) boff[tid] = ws[wv] + incl - v;
}

// adds block offsets; writes row_start/cursor AND the contiguous dst runs
// (csr_dst[v .. v+deg] = gid) — coalesced partition of [0, N_TOT), no scatter.
__global__ __launch_bounds__(256) void scan_add(int* __restrict__ row_start,
                                                const int* __restrict__ boff,
                                                const int* __restrict__ deg,
                                                int* __restrict__ cursor,
                                                u16* __restrict__ csr_dst, int n) {
  int gid = blockIdx.x * 256 + threadIdx.x;
  if (gid < n) {
    int v = row_start[gid] + boff[blockIdx.x];
    row_start[gid] = v;
    cursor[gid] = v;
    int cnt = deg[gid] + 1;
    u16 g16 = (u16)gid;
    for (int k = 0; k < cnt; k++) csr_dst[v + k] = g16;
  }
}

// scatter only src, as u16: halves the scatter footprint (array 1.7 MB).
__global__ void fill_csr(const int* __restrict__ ei, const int* __restrict__ flags,
                         int* __restrict__ cursor, u16* __restrict__ csr_src,
                         int nE, int nN) {
  int e = blockIdx.x * blockDim.x + threadIdx.x;
  if (e >= nE + nN) return;
  int s, d;
  if (e < nE) { int i64 = flags[1]; s = eget(ei, e, i64); d = eget(ei, nE + e, i64); }
  else        { s = e - nE; d = s; }
  int p = atomicAdd(&cursor[d], 1);
  csr_src[p] = (u16)s;
}

// ---------------- MFMA GEMM: H[M,NCOLS] = X[M,128] @ W[128,NCOLS] ----------------
// One wave per 16-row tile. B from fragment-ordered Wf (L2-resident). No LDS.
// FUSE_A (layers 1/2): head h owns tiles 2h,2h+1 -> logits in epilogue.
// CMAJOR+FUSE3 (layer 3): class-major store and head-masked logit accumulation.
template <int NT, int NCOLS, int STRIDE, bool FUSE_A, bool CMAJOR, bool FUSE3>
__global__ __launch_bounds__(256) void gemm_mfma(const u16* __restrict__ X,
                                                 const u16* __restrict__ Wf,
                                                 const u16* __restrict__ attS,
                                                 const u16* __restrict__ attD,
                                                 u16* __restrict__ H,
                                                 float* __restrict__ a_s,
                                                 float* __restrict__ a_d, int M) {
  // readfirstlane: prove wave-uniformity of the wave id to the compiler (SGPR loops/addrs)
  const int wid = __builtin_amdgcn_readfirstlane(threadIdx.x >> 6);
  const int lane = threadIdx.x & 63;
  const int row0 = (blockIdx.x * 4 + wid) * 16;
  if (row0 >= M) return;
  const int qr = lane >> 4;   // quad: k-subchunk for A/B, row group for C/D
  const int ln = lane & 15;   // A row within tile / C col within tile

  float4v acc[NT];
#pragma unroll
  for (int t = 0; t < NT; t++) acc[t] = (float4v){0.f, 0.f, 0.f, 0.f};

  const short8* Wf8 = (const short8*)Wf;  // [(t*4 + c)*64 + lane]
  const u16* xrow = X + (size_t)(row0 + ln) * 128 + qr * 8;

#pragma unroll
  for (int c = 0; c < 4; c++) {
    short8 afrag = *(const short8*)(xrow + c * 32);
#pragma unroll
    for (int t = 0; t < NT; t++) {
      short8 bfrag = Wf8[(t * 4 + c) * 64 + lane];
      acc[t] = __builtin_amdgcn_mfma_f32_16x16x32_bf16(afrag, bfrag, acc[t], 0, 0, 0);
    }
  }

  // store H (D layout: row = qr*4 + i, col = t*16 + ln)
#pragma unroll
  for (int t = 0; t < NT; t++) {
    int col = t * 16 + ln;
    if (col < NCOLS) {
      int off;
      if constexpr (CMAJOR) {
        int h = (col >= 141) ? 3 : (col >= 94) ? 2 : (col >= 47) ? 1 : 0;
        int c = col - h * 47;
        off = c * 4 + h;
      } else {
        off = col;
      }
#pragma unroll
      for (int i = 0; i < 4; i++) {
        H[(size_t)(row0 + qr * 4 + i) * STRIDE + off] = f2b(acc[t][i]);
      }
    }
  }

  if constexpr (FUSE_A) {
    float aSf[NT], aDf[NT];
#pragma unroll
    for (int t = 0; t < NT; t++) {
      aSf[t] = b2f(attS[t * 16 + ln]);
      aDf[t] = b2f(attD[t * 16 + ln]);
    }
#pragma unroll
    for (int h = 0; h < 4; h++) {
#pragma unroll
      for (int i = 0; i < 4; i++) {
        float s = acc[2 * h][i] * aSf[2 * h] + acc[2 * h + 1][i] * aSf[2 * h + 1];
        float d = acc[2 * h][i] * aDf[2 * h] + acc[2 * h + 1][i] * aDf[2 * h + 1];
#pragma unroll
        for (int m = 1; m < 16; m <<= 1) {
          s += __shfl_xor(s, m, 64);
          d += __shfl_xor(d, m, 64);
        }
        if (ln == 0) {
          int r = row0 + qr * 4 + i;
          a_s[r * 4 + h] = s;
          a_d[r * 4 + h] = d;
        }
      }
    }
  }

  if constexpr (FUSE3) {
    // a_s[n][h] = sum_c H[n][h*47+c] * attS[h*47+c]; col = h*47+c indexes attS directly.
    float sh[4][4], dh[4][4];  // [head][i]
#pragma unroll
    for (int h = 0; h < 4; h++)
#pragma unroll
      for (int i = 0; i < 4; i++) { sh[h][i] = 0.f; dh[h][i] = 0.f; }
#pragma unroll
    for (int t = 0; t < NT; t++) {
      int col = t * 16 + ln;
      bool v = (col < NCOLS);
      float aS = v ? b2f(attS[col]) : 0.f;
      float aD = v ? b2f(attD[col]) : 0.f;
      int hh = (col >= 141) ? 3 : (col >= 94) ? 2 : (col >= 47) ? 1 : 0;
      float aS0 = (hh == 0) ? aS : 0.f, aS1 = (hh == 1) ? aS : 0.f;
      float aS2 = (hh == 2) ? aS : 0.f, aS3 = (hh == 3) ? aS : 0.f;
      float aD0 = (hh == 0) ? aD : 0.f, aD1 = (hh == 1) ? aD : 0.f;
      float aD2 = (hh == 2) ? aD : 0.f, aD3 = (hh == 3) ? aD : 0.f;
#pragma unroll
      for (int i = 0; i < 4; i++) {
        float a = acc[t][i];
        sh[0][i] += a * aS0; sh[1][i] += a * aS1;
        sh[2][i] += a * aS2; sh[3][i] += a * aS3;
        dh[0][i] += a * aD0; dh[1][i] += a * aD1;
        dh[2][i] += a * aD2; dh[3][i] += a * aD3;
      }
    }
#pragma unroll
    for (int h = 0; h < 4; h++) {
#pragma unroll
      for (int i = 0; i < 4; i++) {
        float s = sh[h][i], d = dh[h][i];
#pragma unroll
        for (int m = 1; m < 16; m <<= 1) {
          s += __shfl_xor(s, m, 64);
          d += __shfl_xor(d, m, 64);
        }
        if (ln == 0) {
          int r = row0 + qr * 4 + i;
          a_s[r * 4 + h] = s;
          a_d[r * 4 + h] = d;
        }
      }
    }
  }
}

// ---------------- per-edge softmax weights (unnormalized, packed bf16x4) ----------------
// w[e][h] = exp(leaky(a_s[src][h] + a_d[dst][h])) as bf16. Self-normalizing: den sums
// the same bf16 values, so ratios carry only ~2^-9 relative error.
__global__ __launch_bounds__(256) void edge_weights(const u16* __restrict__ csr_src,
                                                    const u16* __restrict__ csr_dst,
                                                    const float* __restrict__ a_s,
                                                    const float* __restrict__ a_d,
                                                    uint2* __restrict__ w, int nE) {
  int e = blockIdx.x * blockDim.x + threadIdx.x;
  if (e >= nE) return;
  int s = csr_src[e], d = csr_dst[e];
  float4 as = ((const float4*)a_s)[s];
  float4 ad = ((const float4*)a_d)[d];
  float w0 = __expf(lrelu(as.x + ad.x));
  float w1 = __expf(lrelu(as.y + ad.y));
  float w2 = __expf(lrelu(as.z + ad.z));
  float w3 = __expf(lrelu(as.w + ad.w));
  uint2 o;
  o.x = ((uint32)f2b(w1) << 16) | (uint32)f2b(w0);
  o.y = ((uint32)f2b(w3) << 16) | (uint32)f2b(w2);
  w[e] = o;
}

// ---------------- aggregation (one node per wave; wave-uniform scalar metadata) ----------

// layers 1/2: lane L owns cols 2L,2L+1 (head L>>4). One uint gather/edge/lane.
__global__ __launch_bounds__(256) void aggregate12(const u16* __restrict__ h,
                                                   const u16* __restrict__ wbuf,
                                                   const int* __restrict__ row_start,
                                                   const u16* __restrict__ csr_src,
                                                   const u16* __restrict__ bias,
                                                   u16* __restrict__ out, int nN) {
  const int lane = threadIdx.x & 63;
  const int wid = __builtin_amdgcn_readfirstlane(threadIdx.x >> 6);  // SGPR wave id
  const int n = blockIdx.x * 4 + wid;
  if (n >= nN) return;
  const int hL = lane >> 4;  // head of cols 2L, 2L+1
  const uint32* h32 = (const uint32*)h;
  const float bias0 = b2f(bias[2 * lane]);
  const float bias1 = b2f(bias[2 * lane + 1]);
  int beg = row_start[n], end = row_start[n + 1];

  float acc0 = 0.f, acc1 = 0.f, den = 0.f;
  int e = beg;
  for (; e + 3 < end; e += 4) {
    int s[4];
    u16 wv[4];
    uint32 g[4];
#pragma unroll
    for (int j = 0; j < 4; j++) s[j] = csr_src[e + j];
#pragma unroll
    for (int j = 0; j < 4; j++) wv[j] = wbuf[(e + j) * 4 + hL];
#pragma unroll
    for (int j = 0; j < 4; j++) g[j] = h32[s[j] * 64 + lane];
#pragma unroll
    for (int j = 0; j < 4; j++) {
      float w = b2f(wv[j]);
      den += w;
      acc0 += w * lo_bf(g[j]);
      acc1 += w * hi_bf(g[j]);
    }
  }
  for (; e < end; ++e) {
    int s = csr_src[e];
    float w = b2f(wbuf[e * 4 + hL]);
    uint32 g = h32[s * 64 + lane];
    den += w;
    acc0 += w * lo_bf(g);
    acc1 += w * hi_bf(g);
  }
  float inv = 1.0f / den;
  float o0 = fmaxf(acc0 * inv + bias0, 0.f);  // relu between layers
  float o1 = fmaxf(acc1 * inv + bias1, 0.f);
  uint32 packed = ((uint32)f2b(o1) << 16) | (uint32)f2b(o0);
  ((uint32*)out)[n * 64 + lane] = packed;
}

// layer 3: class-major h3 (uint2 gather = 4 head vals for class `lane`),
// mean over heads + bias + log_softmax.
__global__ __launch_bounds__(256) void aggregate3(const u16* __restrict__ h3,
                                                  const uint2* __restrict__ wbuf,
                                                  const int* __restrict__ row_start,
                                                  const u16* __restrict__ csr_src,
                                                  const u16* __restrict__ b3,
                                                  const int* __restrict__ flags,
                                                  void* __restrict__ out, int nN) {
  const int lane = threadIdx.x & 63;
  const int wid = __builtin_amdgcn_readfirstlane(threadIdx.x >> 6);  // SGPR wave id
  const int n = blockIdx.x * 4 + wid;
  if (n >= nN) return;
  const bool act = lane < 47;
  const int lidx = act ? lane : 0;
  const float b3v = act ? b2f(b3[lane]) : 0.f;
  const int isf32 = flags[0];
  const uint2* h3v = (const uint2*)h3;  // row = 48 uint2
  int beg = row_start[n], end = row_start[n + 1];

  float den0 = 0.f, den1 = 0.f, den2 = 0.f, den3 = 0.f;
  float acc0 = 0.f, acc1 = 0.f, acc2 = 0.f, acc3 = 0.f;
  int e = beg;
  for (; e + 3 < end; e += 4) {
    int s[4];
    uint2 wp[4];
    uint2 g[4];
#pragma unroll
    for (int j = 0; j < 4; j++) s[j] = csr_src[e + j];
#pragma unroll
    for (int j = 0; j < 4; j++) wp[j] = wbuf[e + j];
#pragma unroll
    for (int j = 0; j < 4; j++) g[j] = h3v[(size_t)s[j] * 48 + lidx];
#pragma unroll
    for (int j = 0; j < 4; j++) {
      float w0 = lo_bf(wp[j].x), w1 = hi_bf(wp[j].x);
      float w2 = lo_bf(wp[j].y), w3 = hi_bf(wp[j].y);
      den0 += w0; den1 += w1; den2 += w2; den3 += w3;
      acc0 += w0 * lo_bf(g[j].x);
      acc1 += w1 * hi_bf(g[j].x);
      acc2 += w2 * lo_bf(g[j].y);
      acc3 += w3 * hi_bf(g[j].y);
    }
  }
  for (; e < end; ++e) {
    int s = csr_src[e];
    uint2 wp = wbuf[e];
    uint2 g = h3v[(size_t)s * 48 + lidx];
    float w0 = lo_bf(wp.x), w1 = hi_bf(wp.x);
    float w2 = lo_bf(wp.y), w3 = hi_bf(wp.y);
    den0 += w0; den1 += w1; den2 += w2; den3 += w3;
    acc0 += w0 * lo_bf(g.x);
    acc1 += w1 * hi_bf(g.x);
    acc2 += w2 * lo_bf(g.y);
    acc3 += w3 * hi_bf(g.y);
  }
  float val = act ? 0.25f * (acc0 / den0 + acc1 / den1 + acc2 / den2 + acc3 / den3) + b3v
                  : -1e30f;
  float mx = val;
#pragma unroll
  for (int m = 1; m < 64; m <<= 1) mx = fmaxf(mx, __shfl_xor(mx, m, 64));
  float ex = act ? __expf(val - mx) : 0.f;
  float sm = ex;
#pragma unroll
  for (int m = 1; m < 64; m <<= 1) sm += __shfl_xor(sm, m, 64);
  float lse = mx + __logf(sm);
  if (act) {
    float r = val - lse;
    if (isf32) ((float*)out)[n * 47 + lane] = r;
    else       ((u16*)out)[n * 47 + lane] = f2b(r);
  }
}

// ---------------- launch ----------------

extern "C" void kernel_launch(void* const* d_in, const int* in_sizes, int n_in,
                              void* d_out, int out_size, void* d_ws, size_t ws_size,
                              hipStream_t stream) {
  const void* x   = d_in[0];
  const void* ei  = d_in[1];
  const void* W1  = d_in[2];
  const void* a1s = d_in[3];
  const void* a1d = d_in[4];
  const void* b1  = d_in[5];
  const void* W2  = d_in[6];
  const void* a2s = d_in[7];
  const void* a2d = d_in[8];
  const void* b2  = d_in[9];
  const void* W3  = d_in[10];
  const void* a3s = d_in[11];
  const void* a3d = d_in[12];
  const void* b3  = d_in[13];
  const int* ei32 = (const int*)ei;

  auto au = [](size_t v) { return (v + 255) & ~(size_t)255; };
  char* p = (char*)d_ws;
  int* flags     = (int*)p; p += 256;
  u16* wt        = (u16*)p; p += au((size_t)58023 * 2);
  u16* Wf1       = (u16*)p; p += au((size_t)16384 * 2);
  u16* Wf2       = (u16*)p; p += au((size_t)16384 * 2);
  u16* Wf3       = (u16*)p; p += au((size_t)24576 * 2);
  int* deg       = (int*)p; p += au((size_t)N_NODES * 4);
  int* row_start = (int*)p; p += au((size_t)(N_NODES + 1) * 4);
  int* cursor    = (int*)p; p += au((size_t)N_NODES * 4);
  int* bsum      = (int*)p; p += au((size_t)SCAN_BLOCKS * 4);
  int* boff      = (int*)p; p += au((size_t)SCAN_BLOCKS * 4);
  u16* csr_src   = (u16*)p; p += au((size_t)N_TOT * 2);
  u16* csr_dst   = (u16*)p; p += au((size_t)N_TOT * 2);
  uint2* wbuf    = (uint2*)p; p += au((size_t)N_TOT * 8);
  float* a_s     = (float*)p; p += au((size_t)N_NODES * 4 * 4);
  float* a_d     = (float*)p; p += au((size_t)N_NODES * 4 * 4);
  u16* x_c       = (u16*)p; p += au((size_t)N_NODES * 128 * 2);
  u16* hA        = (u16*)p; p += au((size_t)N_NODES * 128 * 2);
  u16* h3        = (u16*)p; p += au((size_t)N_NODES * 192 * 2);
  u16* hB        = x_c;  // x_c is dead after layer-1 GEMM; reuse as hB

  const u16* a1sc = wt + 16384;
  const u16* a1dc = wt + 16512;
  const u16* b1c  = wt + 16640;
  const u16* a2sc = wt + 33152;
  const u16* a2dc = wt + 33280;
  const u16* b2c  = wt + 33408;
  const u16* a3sc = wt + 57600;
  const u16* a3dc = wt + 57788;
  const u16* b3c  = wt + 57976;

  const int nodeBlocks = (N_NODES + 3) / 4;        // one wave per node
  const int gemmBlocks = (N_NODES / 16 + 3) / 4;   // wave per 16-row tile: 782
  const int edgeBlocks = (N_TOT + 255) / 256;

  // dtype detection + normalization (fp32/bf16 floats, int64/int32 edges)
  detect_mode<<<1, 256, 0, stream>>>((const u16*)x, ei32, flags);
  convert_x4<<<(N_NODES * 128 / 4 + 255) / 256, 256, 0, stream>>>(x, flags, x_c,
                                                                  N_NODES * 128 / 4);
  reorder_all<<<229, 256, 0, stream>>>(W1, W2, W3, a1s, a1d, b1, a2s, a2d, b2,
                                       a3s, a3d, b3, flags, Wf1, Wf2, Wf3, wt);

  // CSR build; u16 ids; dst written as contiguous runs in scan_add (no dst scatter)
  hipMemsetAsync(deg, 0, (size_t)N_NODES * 4, stream);
  count_deg<<<(N_EDGES + 255) / 256, 256, 0, stream>>>(ei32, flags, deg, N_EDGES);
  scan_blocks<<<SCAN_BLOCKS, 256, 0, stream>>>(deg, row_start, bsum, N_NODES);
  scan_bsum<<<1, 256, 0, stream>>>(bsum, boff, &row_start[N_NODES], SCAN_BLOCKS);
  scan_add<<<SCAN_BLOCKS, 256, 0, stream>>>(row_start, boff, deg, cursor, csr_dst,
                                            N_NODES);
  fill_csr<<<edgeBlocks, 256, 0, stream>>>(ei32, flags, cursor, csr_src,
                                           N_EDGES, N_NODES);

  // layer 1 (attention logits fused into GEMM epilogue)
  gemm_mfma<8, 128, 128, true, false, false><<<gemmBlocks, 256, 0, stream>>>(
      x_c, Wf1, a1sc, a1dc, hA, a_s, a_d, N_NODES);
  edge_weights<<<edgeBlocks, 256, 0, stream>>>(csr_src, csr_dst, a_s, a_d, wbuf, N_TOT);
  aggregate12<<<nodeBlocks, 256, 0, stream>>>(hA, (const u16*)wbuf, row_start, csr_src,
                                              b1c, hB, N_NODES);

  // layer 2
  gemm_mfma<8, 128, 128, true, false, false><<<gemmBlocks, 256, 0, stream>>>(
      hB, Wf2, a2sc, a2dc, hA, a_s, a_d, N_NODES);
  edge_weights<<<edgeBlocks, 256, 0, stream>>>(csr_src, csr_dst, a_s, a_d, wbuf, N_TOT);
  aggregate12<<<nodeBlocks, 256, 0, stream>>>(hA, (const u16*)wbuf, row_start, csr_src,
                                              b2c, hB, N_NODES);

  // layer 3 (h3 class-major; logits fused into GEMM epilogue via head-masked reduce)
  gemm_mfma<12, 188, 192, false, true, true><<<gemmBlocks, 256, 0, stream>>>(
      hB, Wf3, a3sc, a3dc, h3, a_s, a_d, N_NODES);
  edge_weights<<<edgeBlocks, 256, 0, stream>>>(csr_src, csr_dst, a_s, a_d, wbuf, N_TOT);
  aggregate3<<<nodeBlocks, 256, 0, stream>>>(h3, wbuf, row_start, csr_src, b3c, flags,
                                             d_out, N_NODES);
}

// Round 15
// 384.011 us; speedup vs baseline: 1.0578x; 1.0578x over previous
//
#include <hip/hip_runtime.h>

typedef unsigned short u16;
typedef unsigned int uint32;
typedef __attribute__((ext_vector_type(8))) short short8;
typedef __attribute__((ext_vector_type(4))) float float4v;

#define N_NODES 50000
#define N_EDGES 800000
#define N_TOT   850000
#define SCAN_BLOCKS ((N_NODES + 255) / 256)

__device__ __forceinline__ float b2f(u16 u) {
  return __uint_as_float(((unsigned int)u) << 16);
}
__device__ __forceinline__ u16 f2b(float f) {
  unsigned int x = __float_as_uint(f);
  unsigned int r = (x + 0x7fffu + ((x >> 16) & 1u)) >> 16;
  return (u16)r;
}
__device__ __forceinline__ float lo_bf(uint32 g) { return __uint_as_float(g << 16); }
__device__ __forceinline__ float hi_bf(uint32 g) { return __uint_as_float(g & 0xffff0000u); }
__device__ __forceinline__ u16 conv_elem(const void* src, int i, int isf32) {
  if (isf32) return f2b(((const float*)src)[i]);
  return ((const u16*)src)[i];
}
__device__ __forceinline__ float lrelu(float a) { return (a >= 0.f) ? a : 0.2f * a; }
// edge_index element i (flat [2,E]); int64 mode reads low word (ids < 2^31)
__device__ __forceinline__ int eget(const int* __restrict__ ei, int i, int isI64) {
  return isI64 ? ei[2 * i] : ei[i];
}

// ---------------- dtype detection ----------------
// flags[0]=1 if float inputs are fp32 (else bf16); flags[1]=1 if edge_index is int64.
__global__ void detect_mode(const u16* __restrict__ x16, const int* __restrict__ ei32,
                            int* __restrict__ flags) {
  __shared__ int sh_f32, sh_i32;
  int tid = threadIdx.x;
  if (tid == 0) { sh_f32 = 0; sh_i32 = 0; }
  __syncthreads();
  int emax = 0;
  for (int i = tid; i < 4096; i += 256) {
    int e = (x16[i] >> 7) & 0xFF;  // bf16 exponent field
    emax = emax > e ? emax : e;
  }
  if (emax >= 140) atomicOr(&sh_f32, 1);           // |v| >= 2^13: impossible for real bf16 N(0,1)
  if (ei32[2 * tid + 1] != 0) atomicOr(&sh_i32, 1); // nonzero odd word => int32 data
  __syncthreads();
  if (tid == 0) { flags[0] = sh_f32; flags[1] = sh_i32 ? 0 : 1; }
}

__global__ void convert_x4(const void* __restrict__ x, const int* __restrict__ flags,
                           u16* __restrict__ out, int n4) {
  int i = blockIdx.x * blockDim.x + threadIdx.x;
  if (i >= n4) return;
  if (flags[0]) {
    float4 v = ((const float4*)x)[i];
    ushort4 o;
    o.x = f2b(v.x); o.y = f2b(v.y); o.z = f2b(v.z); o.w = f2b(v.w);
    ((ushort4*)out)[i] = o;
  } else {
    ((ushort4*)out)[i] = ((const ushort4*)x)[i];
  }
}

// ---------------- W fragment reorder (direct from raw inputs) + att/bias convert ----------
// Wf[t][c][lane][j] = W[c*32 + (lane>>4)*8 + j][t*16 + (lane&15)], zero-padded.
// Tail threads (idx >= 57344) convert the 1063 att/bias elements into wt.
__global__ void reorder_all(const void* W1, const void* W2, const void* W3,
                            const void* a1s, const void* a1d, const void* b1,
                            const void* a2s, const void* a2d, const void* b2,
                            const void* a3s, const void* a3d, const void* b3,
                            const int* __restrict__ flags,
                            u16* __restrict__ Wf1, u16* __restrict__ Wf2,
                            u16* __restrict__ Wf3, u16* __restrict__ wt) {
  int idx = blockIdx.x * blockDim.x + threadIdx.x;
  int f32 = flags[0];
  if (idx < 57344) {
    const void* W; u16* Wf; int NCOLS, li;
    if (idx < 16384)      { W = W1; Wf = Wf1; NCOLS = 128; li = idx; }
    else if (idx < 32768) { W = W2; Wf = Wf2; NCOLS = 128; li = idx - 16384; }
    else                  { W = W3; Wf = Wf3; NCOLS = 188; li = idx - 32768; }
    int j = li & 7;
    int l = (li >> 3) & 63;
    int c = (li >> 9) & 3;
    int t = li >> 11;
    int k = c * 32 + (l >> 4) * 8 + j;
    int n = t * 16 + (l & 15);
    Wf[li] = (n < NCOLS) ? conv_elem(W, k * NCOLS + n, f32) : (u16)0;
  } else {
    int li = idx - 57344;
    const void* src; int off;
    if (li < 128)       { src = a1s; off = 16384; }
    else if (li < 256)  { src = a1d; off = 16512; li -= 128; }
    else if (li < 384)  { src = b1;  off = 16640; li -= 256; }
    else if (li < 512)  { src = a2s; off = 33152; li -= 384; }
    else if (li < 640)  { src = a2d; off = 33280; li -= 512; }
    else if (li < 768)  { src = b2;  off = 33408; li -= 640; }
    else if (li < 956)  { src = a3s; off = 57600; li -= 768; }
    else if (li < 1144) { src = a3d; off = 57788; li -= 956; }
    else if (li < 1191) { src = b3;  off = 57976; li -= 1144; }
    else return;
    wt[off + li] = conv_elem(src, li, f32);
  }
}

// ---------------- CSR build ----------------
// deg is zeroed via hipMemsetAsync; self-loop +1 folded into scan_blocks.
// Scatter happens on a u16 array (minimal dirty-line footprint); a streaming
// widen pass produces the int32 copy the aggregates read via SCALAR loads
// (s_load is dword-granular — u16 uniform loads fall back to vector ops).

__global__ void count_deg(const int* __restrict__ ei, const int* __restrict__ flags,
                          int* __restrict__ deg, int nE) {
  int e = blockIdx.x * blockDim.x + threadIdx.x;
  if (e < nE) atomicAdd(&deg[eget(ei, nE + e, flags[1])], 1);
}

// ---- device-wide exclusive scan of (deg+1) (3 kernels, all CUs) ----
__global__ __launch_bounds__(256) void scan_blocks(const int* __restrict__ deg,
                                                   int* __restrict__ part,
                                                   int* __restrict__ bsum, int n) {
  __shared__ int ws[4];
  int tid = threadIdx.x;
  int gid = blockIdx.x * 256 + tid;
  int lane = tid & 63, wv = tid >> 6;
  int v = (gid < n) ? (deg[gid] + 1) : 0;  // +1 = self-loop
  int incl = v;
#pragma unroll
  for (int off = 1; off < 64; off <<= 1) {
    int t = __shfl_up(incl, off, 64);
    if (lane >= off) incl += t;
  }
  if (lane == 63) ws[wv] = incl;
  __syncthreads();
  if (tid == 0) {
    int s = 0;
#pragma unroll
    for (int w = 0; w < 4; w++) { int t = ws[w]; ws[w] = s; s += t; }
    bsum[blockIdx.x] = s;
  }
  __syncthreads();
  if (gid < n) part[gid] = ws[wv] + incl - v;  // exclusive within block
}

__global__ __launch_bounds__(256) void scan_bsum(const int* __restrict__ bsum,
                                                 int* __restrict__ boff,
                                                 int* __restrict__ total, int nb) {
  __shared__ int ws[4];
  int tid = threadIdx.x;
  int lane = tid & 63, wv = tid >> 6;
  int v = (tid < nb) ? bsum[tid] : 0;
  int incl = v;
#pragma unroll
  for (int off = 1; off < 64; off <<= 1) {
    int t = __shfl_up(incl, off, 64);
    if (lane >= off) incl += t;
  }
  if (lane == 63) ws[wv] = incl;
  __syncthreads();
  if (tid == 0) {
    int s = 0;
#pragma unroll
    for (int w = 0; w < 4; w++) { int t = ws[w]; ws[w] = s; s += t; }
    *total = s;
  }
  __syncthreads();
  if (tid < nb) boff[tid] = ws[wv] + incl - v;
}

// adds block offsets; writes row_start/cursor AND the contiguous dst runs
// (csr_dst[v .. v+deg] = gid) — coalesced partition of [0, N_TOT), no scatter.
__global__ __launch_bounds__(256) void scan_add(int* __restrict__ row_start,
                                                const int* __restrict__ boff,
                                                const int* __restrict__ deg,
                                                int* __restrict__ cursor,
                                                u16* __restrict__ csr_dst, int n) {
  int gid = blockIdx.x * 256 + threadIdx.x;
  if (gid < n) {
    int v = row_start[gid] + boff[blockIdx.x];
    row_start[gid] = v;
    cursor[gid] = v;
    int cnt = deg[gid] + 1;
    u16 g16 = (u16)gid;
    for (int k = 0; k < cnt; k++) csr_dst[v + k] = g16;
  }
}

// scatter only src, as u16: minimal scatter footprint (array 1.7 MB).
__global__ void fill_csr(const int* __restrict__ ei, const int* __restrict__ flags,
                         int* __restrict__ cursor, u16* __restrict__ csr_src,
                         int nE, int nN) {
  int e = blockIdx.x * blockDim.x + threadIdx.x;
  if (e >= nE + nN) return;
  int s, d;
  if (e < nE) { int i64 = flags[1]; s = eget(ei, e, i64); d = eget(ei, nE + e, i64); }
  else        { s = e - nE; d = s; }
  int p = atomicAdd(&cursor[d], 1);
  csr_src[p] = (u16)s;
}

// streaming u16 -> int32 widen so aggregates get scalar-loadable metadata.
__global__ void widen_src(const u16* __restrict__ src16, int* __restrict__ src32, int n) {
  int i = blockIdx.x * blockDim.x + threadIdx.x;
  if (i < n) src32[i] = (int)src16[i];
}

// ---------------- MFMA GEMM: H[M,NCOLS] = X[M,128] @ W[128,NCOLS] ----------------
// One wave per 16-row tile. B from fragment-ordered Wf (L2-resident). No LDS.
// FUSE_A (layers 1/2): head h owns tiles 2h,2h+1 -> logits in epilogue.
// CMAJOR+FUSE3 (layer 3): class-major store and head-masked logit accumulation.
template <int NT, int NCOLS, int STRIDE, bool FUSE_A, bool CMAJOR, bool FUSE3>
__global__ __launch_bounds__(256) void gemm_mfma(const u16* __restrict__ X,
                                                 const u16* __restrict__ Wf,
                                                 const u16* __restrict__ attS,
                                                 const u16* __restrict__ attD,
                                                 u16* __restrict__ H,
                                                 float* __restrict__ a_s,
                                                 float* __restrict__ a_d, int M) {
  // readfirstlane: prove wave-uniformity of the wave id to the compiler (SGPR loops/addrs)
  const int wid = __builtin_amdgcn_readfirstlane(threadIdx.x >> 6);
  const int lane = threadIdx.x & 63;
  const int row0 = (blockIdx.x * 4 + wid) * 16;
  if (row0 >= M) return;
  const int qr = lane >> 4;   // quad: k-subchunk for A/B, row group for C/D
  const int ln = lane & 15;   // A row within tile / C col within tile

  float4v acc[NT];
#pragma unroll
  for (int t = 0; t < NT; t++) acc[t] = (float4v){0.f, 0.f, 0.f, 0.f};

  const short8* Wf8 = (const short8*)Wf;  // [(t*4 + c)*64 + lane]
  const u16* xrow = X + (size_t)(row0 + ln) * 128 + qr * 8;

#pragma unroll
  for (int c = 0; c < 4; c++) {
    short8 afrag = *(const short8*)(xrow + c * 32);
#pragma unroll
    for (int t = 0; t < NT; t++) {
      short8 bfrag = Wf8[(t * 4 + c) * 64 + lane];
      acc[t] = __builtin_amdgcn_mfma_f32_16x16x32_bf16(afrag, bfrag, acc[t], 0, 0, 0);
    }
  }

  // store H (D layout: row = qr*4 + i, col = t*16 + ln)
#pragma unroll
  for (int t = 0; t < NT; t++) {
    int col = t * 16 + ln;
    if (col < NCOLS) {
      int off;
      if constexpr (CMAJOR) {
        int h = (col >= 141) ? 3 : (col >= 94) ? 2 : (col >= 47) ? 1 : 0;
        int c = col - h * 47;
        off = c * 4 + h;
      } else {
        off = col;
      }
#pragma unroll
      for (int i = 0; i < 4; i++) {
        H[(size_t)(row0 + qr * 4 + i) * STRIDE + off] = f2b(acc[t][i]);
      }
    }
  }

  if constexpr (FUSE_A) {
    float aSf[NT], aDf[NT];
#pragma unroll
    for (int t = 0; t < NT; t++) {
      aSf[t] = b2f(attS[t * 16 + ln]);
      aDf[t] = b2f(attD[t * 16 + ln]);
    }
#pragma unroll
    for (int h = 0; h < 4; h++) {
#pragma unroll
      for (int i = 0; i < 4; i++) {
        float s = acc[2 * h][i] * aSf[2 * h] + acc[2 * h + 1][i] * aSf[2 * h + 1];
        float d = acc[2 * h][i] * aDf[2 * h] + acc[2 * h + 1][i] * aDf[2 * h + 1];
#pragma unroll
        for (int m = 1; m < 16; m <<= 1) {
          s += __shfl_xor(s, m, 64);
          d += __shfl_xor(d, m, 64);
        }
        if (ln == 0) {
          int r = row0 + qr * 4 + i;
          a_s[r * 4 + h] = s;
          a_d[r * 4 + h] = d;
        }
      }
    }
  }

  if constexpr (FUSE3) {
    // a_s[n][h] = sum_c H[n][h*47+c] * attS[h*47+c]; col = h*47+c indexes attS directly.
    float sh[4][4], dh[4][4];  // [head][i]
#pragma unroll
    for (int h = 0; h < 4; h++)
#pragma unroll
      for (int i = 0; i < 4; i++) { sh[h][i] = 0.f; dh[h][i] = 0.f; }
#pragma unroll
    for (int t = 0; t < NT; t++) {
      int col = t * 16 + ln;
      bool v = (col < NCOLS);
      float aS = v ? b2f(attS[col]) : 0.f;
      float aD = v ? b2f(attD[col]) : 0.f;
      int hh = (col >= 141) ? 3 : (col >= 94) ? 2 : (col >= 47) ? 1 : 0;
      float aS0 = (hh == 0) ? aS : 0.f, aS1 = (hh == 1) ? aS : 0.f;
      float aS2 = (hh == 2) ? aS : 0.f, aS3 = (hh == 3) ? aS : 0.f;
      float aD0 = (hh == 0) ? aD : 0.f, aD1 = (hh == 1) ? aD : 0.f;
      float aD2 = (hh == 2) ? aD : 0.f, aD3 = (hh == 3) ? aD : 0.f;
#pragma unroll
      for (int i = 0; i < 4; i++) {
        float a = acc[t][i];
        sh[0][i] += a * aS0; sh[1][i] += a * aS1;
        sh[2][i] += a * aS2; sh[3][i] += a * aS3;
        dh[0][i] += a * aD0; dh[1][i] += a * aD1;
        dh[2][i] += a * aD2; dh[3][i] += a * aD3;
      }
    }
#pragma unroll
    for (int h = 0; h < 4; h++) {
#pragma unroll
      for (int i = 0; i < 4; i++) {
        float s = sh[h][i], d = dh[h][i];
#pragma unroll
        for (int m = 1; m < 16; m <<= 1) {
          s += __shfl_xor(s, m, 64);
          d += __shfl_xor(d, m, 64);
        }
        if (ln == 0) {
          int r = row0 + qr * 4 + i;
          a_s[r * 4 + h] = s;
          a_d[r * 4 + h] = d;
        }
      }
    }
  }
}

// ---------------- per-edge softmax weights (unnormalized, packed bf16x4) ----------------
// w[e][h] = exp(leaky(a_s[src][h] + a_d[dst][h])) as bf16. Self-normalizing: den sums
// the same bf16 values, so ratios carry only ~2^-9 relative error.
__global__ __launch_bounds__(256) void edge_weights(const u16* __restrict__ csr_src,
                                                    const u16* __restrict__ csr_dst,
                                                    const float* __restrict__ a_s,
                                                    const float* __restrict__ a_d,
                                                    uint2* __restrict__ w, int nE) {
  int e = blockIdx.x * blockDim.x + threadIdx.x;
  if (e >= nE) return;
  int s = csr_src[e], d = csr_dst[e];
  float4 as = ((const float4*)a_s)[s];
  float4 ad = ((const float4*)a_d)[d];
  float w0 = __expf(lrelu(as.x + ad.x));
  float w1 = __expf(lrelu(as.y + ad.y));
  float w2 = __expf(lrelu(as.z + ad.z));
  float w3 = __expf(lrelu(as.w + ad.w));
  uint2 o;
  o.x = ((uint32)f2b(w1) << 16) | (uint32)f2b(w0);
  o.y = ((uint32)f2b(w3) << 16) | (uint32)f2b(w2);
  w[e] = o;
}

// ---------------- aggregation (one node per wave; wave-uniform scalar metadata) ----------

// layers 1/2: lane L owns cols 2L,2L+1 (head L>>4). One uint gather/edge/lane.
__global__ __launch_bounds__(256) void aggregate12(const u16* __restrict__ h,
                                                   const u16* __restrict__ wbuf,
                                                   const int* __restrict__ row_start,
                                                   const int* __restrict__ csr_src,
                                                   const u16* __restrict__ bias,
                                                   u16* __restrict__ out, int nN) {
  const int lane = threadIdx.x & 63;
  const int wid = __builtin_amdgcn_readfirstlane(threadIdx.x >> 6);  // SGPR wave id
  const int n = blockIdx.x * 4 + wid;
  if (n >= nN) return;
  const int hL = lane >> 4;  // head of cols 2L, 2L+1
  const uint32* h32 = (const uint32*)h;
  const float bias0 = b2f(bias[2 * lane]);
  const float bias1 = b2f(bias[2 * lane + 1]);
  int beg = row_start[n], end = row_start[n + 1];

  float acc0 = 0.f, acc1 = 0.f, den = 0.f;
  int e = beg;
  for (; e + 3 < end; e += 4) {
    int s[4];
    u16 wv[4];
    uint32 g[4];
#pragma unroll
    for (int j = 0; j < 4; j++) s[j] = csr_src[e + j];
#pragma unroll
    for (int j = 0; j < 4; j++) wv[j] = wbuf[(e + j) * 4 + hL];
#pragma unroll
    for (int j = 0; j < 4; j++) g[j] = h32[s[j] * 64 + lane];
#pragma unroll
    for (int j = 0; j < 4; j++) {
      float w = b2f(wv[j]);
      den += w;
      acc0 += w * lo_bf(g[j]);
      acc1 += w * hi_bf(g[j]);
    }
  }
  for (; e < end; ++e) {
    int s = csr_src[e];
    float w = b2f(wbuf[e * 4 + hL]);
    uint32 g = h32[s * 64 + lane];
    den += w;
    acc0 += w * lo_bf(g);
    acc1 += w * hi_bf(g);
  }
  float inv = 1.0f / den;
  float o0 = fmaxf(acc0 * inv + bias0, 0.f);  // relu between layers
  float o1 = fmaxf(acc1 * inv + bias1, 0.f);
  uint32 packed = ((uint32)f2b(o1) << 16) | (uint32)f2b(o0);
  ((uint32*)out)[n * 64 + lane] = packed;
}

// layer 3: class-major h3 (uint2 gather = 4 head vals for class `lane`),
// mean over heads + bias + log_softmax.
__global__ __launch_bounds__(256) void aggregate3(const u16* __restrict__ h3,
                                                  const uint2* __restrict__ wbuf,
                                                  const int* __restrict__ row_start,
                                                  const int* __restrict__ csr_src,
                                                  const u16* __restrict__ b3,
                                                  const int* __restrict__ flags,
                                                  void* __restrict__ out, int nN) {
  const int lane = threadIdx.x & 63;
  const int wid = __builtin_amdgcn_readfirstlane(threadIdx.x >> 6);  // SGPR wave id
  const int n = blockIdx.x * 4 + wid;
  if (n >= nN) return;
  const bool act = lane < 47;
  const int lidx = act ? lane : 0;
  const float b3v = act ? b2f(b3[lane]) : 0.f;
  const int isf32 = flags[0];
  const uint2* h3v = (const uint2*)h3;  // row = 48 uint2
  int beg = row_start[n], end = row_start[n + 1];

  float den0 = 0.f, den1 = 0.f, den2 = 0.f, den3 = 0.f;
  float acc0 = 0.f, acc1 = 0.f, acc2 = 0.f, acc3 = 0.f;
  int e = beg;
  for (; e + 3 < end; e += 4) {
    int s[4];
    uint2 wp[4];
    uint2 g[4];
#pragma unroll
    for (int j = 0; j < 4; j++) s[j] = csr_src[e + j];
#pragma unroll
    for (int j = 0; j < 4; j++) wp[j] = wbuf[e + j];
#pragma unroll
    for (int j = 0; j < 4; j++) g[j] = h3v[(size_t)s[j] * 48 + lidx];
#pragma unroll
    for (int j = 0; j < 4; j++) {
      float w0 = lo_bf(wp[j].x), w1 = hi_bf(wp[j].x);
      float w2 = lo_bf(wp[j].y), w3 = hi_bf(wp[j].y);
      den0 += w0; den1 += w1; den2 += w2; den3 += w3;
      acc0 += w0 * lo_bf(g[j].x);
      acc1 += w1 * hi_bf(g[j].x);
      acc2 += w2 * lo_bf(g[j].y);
      acc3 += w3 * hi_bf(g[j].y);
    }
  }
  for (; e < end; ++e) {
    int s = csr_src[e];
    uint2 wp = wbuf[e];
    uint2 g = h3v[(size_t)s * 48 + lidx];
    float w0 = lo_bf(wp.x), w1 = hi_bf(wp.x);
    float w2 = lo_bf(wp.y), w3 = hi_bf(wp.y);
    den0 += w0; den1 += w1; den2 += w2; den3 += w3;
    acc0 += w0 * lo_bf(g.x);
    acc1 += w1 * hi_bf(g.x);
    acc2 += w2 * lo_bf(g.y);
    acc3 += w3 * hi_bf(g.y);
  }
  float val = act ? 0.25f * (acc0 / den0 + acc1 / den1 + acc2 / den2 + acc3 / den3) + b3v
                  : -1e30f;
  float mx = val;
#pragma unroll
  for (int m = 1; m < 64; m <<= 1) mx = fmaxf(mx, __shfl_xor(mx, m, 64));
  float ex = act ? __expf(val - mx) : 0.f;
  float sm = ex;
#pragma unroll
  for (int m = 1; m < 64; m <<= 1) sm += __shfl_xor(sm, m, 64);
  float lse = mx + __logf(sm);
  if (act) {
    float r = val - lse;
    if (isf32) ((float*)out)[n * 47 + lane] = r;
    else       ((u16*)out)[n * 47 + lane] = f2b(r);
  }
}

// ---------------- launch ----------------

extern "C" void kernel_launch(void* const* d_in, const int* in_sizes, int n_in,
                              void* d_out, int out_size, void* d_ws, size_t ws_size,
                              hipStream_t stream) {
  const void* x   = d_in[0];
  const void* ei  = d_in[1];
  const void* W1  = d_in[2];
  const void* a1s = d_in[3];
  const void* a1d = d_in[4];
  const void* b1  = d_in[5];
  const void* W2  = d_in[6];
  const void* a2s = d_in[7];
  const void* a2d = d_in[8];
  const void* b2  = d_in[9];
  const void* W3  = d_in[10];
  const void* a3s = d_in[11];
  const void* a3d = d_in[12];
  const void* b3  = d_in[13];
  const int* ei32 = (const int*)ei;

  auto au = [](size_t v) { return (v + 255) & ~(size_t)255; };
  char* p = (char*)d_ws;
  int* flags     = (int*)p; p += 256;
  u16* wt        = (u16*)p; p += au((size_t)58023 * 2);
  u16* Wf1       = (u16*)p; p += au((size_t)16384 * 2);
  u16* Wf2       = (u16*)p; p += au((size_t)16384 * 2);
  u16* Wf3       = (u16*)p; p += au((size_t)24576 * 2);
  int* deg       = (int*)p; p += au((size_t)N_NODES * 4);
  int* row_start = (int*)p; p += au((size_t)(N_NODES + 1) * 4);
  int* cursor    = (int*)p; p += au((size_t)N_NODES * 4);
  int* bsum      = (int*)p; p += au((size_t)SCAN_BLOCKS * 4);
  int* boff      = (int*)p; p += au((size_t)SCAN_BLOCKS * 4);
  u16* csr_src16 = (u16*)p; p += au((size_t)N_TOT * 2);
  u16* csr_dst   = (u16*)p; p += au((size_t)N_TOT * 2);
  int* csr_src32 = (int*)p; p += au((size_t)N_TOT * 4);
  uint2* wbuf    = (uint2*)p; p += au((size_t)N_TOT * 8);
  float* a_s     = (float*)p; p += au((size_t)N_NODES * 4 * 4);
  float* a_d     = (float*)p; p += au((size_t)N_NODES * 4 * 4);
  u16* x_c       = (u16*)p; p += au((size_t)N_NODES * 128 * 2);
  u16* hA        = (u16*)p; p += au((size_t)N_NODES * 128 * 2);
  u16* h3        = (u16*)p; p += au((size_t)N_NODES * 192 * 2);
  u16* hB        = x_c;  // x_c is dead after layer-1 GEMM; reuse as hB

  const u16* a1sc = wt + 16384;
  const u16* a1dc = wt + 16512;
  const u16* b1c  = wt + 16640;
  const u16* a2sc = wt + 33152;
  const u16* a2dc = wt + 33280;
  const u16* b2c  = wt + 33408;
  const u16* a3sc = wt + 57600;
  const u16* a3dc = wt + 57788;
  const u16* b3c  = wt + 57976;

  const int nodeBlocks = (N_NODES + 3) / 4;        // one wave per node
  const int gemmBlocks = (N_NODES / 16 + 3) / 4;   // wave per 16-row tile: 782
  const int edgeBlocks = (N_TOT + 255) / 256;

  // dtype detection + normalization (fp32/bf16 floats, int64/int32 edges)
  detect_mode<<<1, 256, 0, stream>>>((const u16*)x, ei32, flags);
  convert_x4<<<(N_NODES * 128 / 4 + 255) / 256, 256, 0, stream>>>(x, flags, x_c,
                                                                  N_NODES * 128 / 4);
  reorder_all<<<229, 256, 0, stream>>>(W1, W2, W3, a1s, a1d, b1, a2s, a2d, b2,
                                       a3s, a3d, b3, flags, Wf1, Wf2, Wf3, wt);

  // CSR build; u16 scatter + streaming widen; dst as contiguous runs in scan_add
  hipMemsetAsync(deg, 0, (size_t)N_NODES * 4, stream);
  count_deg<<<(N_EDGES + 255) / 256, 256, 0, stream>>>(ei32, flags, deg, N_EDGES);
  scan_blocks<<<SCAN_BLOCKS, 256, 0, stream>>>(deg, row_start, bsum, N_NODES);
  scan_bsum<<<1, 256, 0, stream>>>(bsum, boff, &row_start[N_NODES], SCAN_BLOCKS);
  scan_add<<<SCAN_BLOCKS, 256, 0, stream>>>(row_start, boff, deg, cursor, csr_dst,
                                            N_NODES);
  fill_csr<<<edgeBlocks, 256, 0, stream>>>(ei32, flags, cursor, csr_src16,
                                           N_EDGES, N_NODES);
  widen_src<<<edgeBlocks, 256, 0, stream>>>(csr_src16, csr_src32, N_TOT);

  // layer 1 (attention logits fused into GEMM epilogue)
  gemm_mfma<8, 128, 128, true, false, false><<<gemmBlocks, 256, 0, stream>>>(
      x_c, Wf1, a1sc, a1dc, hA, a_s, a_d, N_NODES);
  edge_weights<<<edgeBlocks, 256, 0, stream>>>(csr_src16, csr_dst, a_s, a_d, wbuf, N_TOT);
  aggregate12<<<nodeBlocks, 256, 0, stream>>>(hA, (const u16*)wbuf, row_start, csr_src32,
                                              b1c, hB, N_NODES);

  // layer 2
  gemm_mfma<8, 128, 128, true, false, false><<<gemmBlocks, 256, 0, stream>>>(
      hB, Wf2, a2sc, a2dc, hA, a_s, a_d, N_NODES);
  edge_weights<<<edgeBlocks, 256, 0, stream>>>(csr_src16, csr_dst, a_s, a_d, wbuf, N_TOT);
  aggregate12<<<nodeBlocks, 256, 0, stream>>>(hA, (const u16*)wbuf, row_start, csr_src32,
                                              b2c, hB, N_NODES);

  // layer 3 (h3 class-major; logits fused into GEMM epilogue via head-masked reduce)
  gemm_mfma<12, 188, 192, false, true, true><<<gemmBlocks, 256, 0, stream>>>(
      hB, Wf3, a3sc, a3dc, h3, a_s, a_d, N_NODES);
  edge_weights<<<edgeBlocks, 256, 0, stream>>>(csr_src16, csr_dst, a_s, a_d, wbuf, N_TOT);
  aggregate3<<<nodeBlocks, 256, 0, stream>>>(h3, wbuf, row_start, csr_src32, b3c, flags,
                                             d_out, N_NODES);
}